// Round 2
// baseline (472.629 us; speedup 1.0000x reference)
//
#include <hip/hip_runtime.h>
#include <stdint.h>

typedef unsigned short u16;
typedef __attribute__((ext_vector_type(4))) float f32x4;
typedef __attribute__((ext_vector_type(8))) __bf16 bf16x8;
typedef __attribute__((ext_vector_type(8))) u16 u16x8;

#define AS1 __attribute__((address_space(1)))
#define AS3 __attribute__((address_space(3)))

// async global->LDS, 16B per lane. LDS dest must be linear in lane id
// (wave-uniform base + lane*16). Direct addrspacecasts (generic->AS1/AS3).
__device__ __forceinline__ void gload16(const void* g, void* l) {
  __builtin_amdgcn_global_load_lds((const AS1 void*)g, (AS3 void*)l, 16, 0, 0);
}

__device__ __forceinline__ float bf2f(u16 u) {
  union { uint32_t i; float f; } v; v.i = ((uint32_t)u) << 16; return v.f;
}
__device__ __forceinline__ u16 f2bf(float f) {  // RTNE, matches numpy/jax
  uint32_t x = __builtin_bit_cast(uint32_t, f);
  x += 0x7fffu + ((x >> 16) & 1u);
  return (u16)(x >> 16);
}
__device__ __forceinline__ float phi_f(float x) { return x > 0.f ? x + 1.f : __expf(x); }

__device__ __forceinline__ f32x4 mfma16(bf16x8 a, bf16x8 b, f32x4 c) {
  return __builtin_amdgcn_mfma_f32_16x16x32_bf16(a, b, c, 0, 0, 0);
}

// ---------------- workspace layout (bytes) — total 249,102,336 (fits: r1 ran) ----
#define OFF_WQT  0ULL
#define OFF_WKT  (OFF_WQT + 524288ULL)
#define OFF_WVT  (OFF_WKT + 524288ULL)
#define OFF_WOT  (OFF_WVT + 524288ULL)           // 2048*2048*2 bf16
#define OFF_PQ   (OFF_WOT + 8388608ULL)          // [128 bh][2048][128] bf16
#define OFF_PKT  (OFF_PQ  + 67108864ULL)         // [128 bh][128 d][2048 s] bf16
#define OFF_VT   (OFF_PKT + 67108864ULL)         // [128 bh][128 d][2048 s] bf16
#define OFF_KVP  (OFF_VT  + 67108864ULL)         // [4 part][128 bh][128][128] f32
#define OFF_KVT  (OFF_KVP + 33554432ULL)         // [128 bh][128 e][128 d] bf16 (kv^T)
#define OFF_KSUM (OFF_KVT + 4194304ULL)          // [128 bh][128] f32
#define OFF_CTX  OFF_PKT                          // alias: pkT dead after mla_ksum
#define WS_NEED  (OFF_KSUM + 65536ULL)

// ---------------- batched square transpose + fp32->bf16 convert ----------------
__global__ __launch_bounds__(256) void mla_transpose_cvt(const float* __restrict__ src,
                                                         u16* __restrict__ dst, int n) {
  __shared__ u16 tile[32][33];
  const int b = blockIdx.z;
  const float* s = src + (size_t)b * n * n;
  u16* d = dst + (size_t)b * n * n;
  const int x = blockIdx.x * 32 + threadIdx.x;
  const int y0 = blockIdx.y * 32 + threadIdx.y;
  #pragma unroll
  for (int i = 0; i < 32; i += 8)
    tile[threadIdx.y + i][threadIdx.x] = f2bf(s[(size_t)(y0 + i) * n + x]);
  __syncthreads();
  const int x2 = blockIdx.y * 32 + threadIdx.x;
  const int y2 = blockIdx.x * 32 + threadIdx.y;
  #pragma unroll
  for (int i = 0; i < 32; i += 8)
    d[(size_t)(y2 + i) * n + x2] = tile[threadIdx.x][threadIdx.y + i];
}

// ---------------- K1: q/k/v projections + phi ----------------
// grid (128 row-tiles, 16 heads), 256 thr. X (fp32) converted in-register to
// bf16 LDS once; the 3 bf16 transposed weights staged per pass via gload16.
__global__ __launch_bounds__(256) void mla_qkv(
    const float* __restrict__ X, const u16* __restrict__ WqT,
    const u16* __restrict__ WkT, const u16* __restrict__ WvT,
    u16* __restrict__ pq, u16* __restrict__ pkT, u16* __restrict__ vT) {
  __shared__ u16 ldsX[128 * 128];
  __shared__ u16 ldsW[128 * 128];
  const int t = threadIdx.x;
  const int rt = blockIdx.x, h = blockIdx.y;
  const int r0 = rt * 128;
  const int b = r0 >> 11;
  const int sl0 = r0 & 2047;
  const int bh = b * 16 + h;
  const u16* Wsrc[3] = { WqT + h * 16384, WkT + h * 16384, WvT + h * 16384 };

  // issue W0 staging first so HBM latency hides under the X conversion
  #pragma unroll
  for (int i = 0; i < 8; ++i)
    gload16(Wsrc[0] + i * 2048 + t * 8, &ldsW[i * 2048 + t * 8]);

  // reg-stage X: fp32 global -> cvt -> bf16 LDS (row-major 128x128)
  const float* Xg = X + (size_t)r0 * 2048 + h * 128;
  #pragma unroll
  for (int j = 0; j < 8; ++j) {
    int e = j * 2048 + t * 8;
    int row = e >> 7, col = e & 127;
    const float* p = Xg + (size_t)row * 2048 + col;
    f32x4 a = *(const f32x4*)p;
    f32x4 c = *(const f32x4*)(p + 4);
    u16x8 wv;
    #pragma unroll
    for (int q = 0; q < 4; ++q) { wv[q] = f2bf(a[q]); wv[4 + q] = f2bf(c[q]); }
    *(u16x8*)&ldsX[e] = wv;
  }
  __syncthreads();   // X writes visible; W0 gload drained

  const int wave = t >> 6, lane = t & 63;
  const int wm = (wave >> 1) * 64, wn = (wave & 1) * 64;
  const int lr = lane & 15, lk = (lane >> 4) * 8, r4 = (lane >> 4) * 4;

  for (int wsel = 0; wsel < 3; ++wsel) {
    if (wsel) {
      __syncthreads();                     // everyone done with previous ldsW
      #pragma unroll
      for (int i = 0; i < 8; ++i)
        gload16(Wsrc[wsel] + i * 2048 + t * 8, &ldsW[i * 2048 + t * 8]);
      __syncthreads();
    }
    f32x4 acc[4][4];
    #pragma unroll
    for (int mb = 0; mb < 4; ++mb)
      #pragma unroll
      for (int nb = 0; nb < 4; ++nb) acc[mb][nb] = (f32x4)0.f;
    #pragma unroll
    for (int ks = 0; ks < 4; ++ks) {
      bf16x8 af[4], bb[4];
      #pragma unroll
      for (int mb = 0; mb < 4; ++mb)
        af[mb] = *(const bf16x8*)&ldsX[(wm + mb * 16 + lr) * 128 + ks * 32 + lk];
      #pragma unroll
      for (int nb = 0; nb < 4; ++nb)
        bb[nb] = *(const bf16x8*)&ldsW[(wn + nb * 16 + lr) * 128 + ks * 32 + lk];
      #pragma unroll
      for (int mb = 0; mb < 4; ++mb)
        #pragma unroll
        for (int nb = 0; nb < 4; ++nb)
          acc[mb][nb] = mfma16(af[mb], bb[nb], acc[mb][nb]);
    }
    if (wsel == 0) {                        // pq: [bh][s][d]
      u16* outq = pq + (size_t)bh * 262144 + (size_t)sl0 * 128;
      #pragma unroll
      for (int mb = 0; mb < 4; ++mb)
        #pragma unroll
        for (int nb = 0; nb < 4; ++nb)
          #pragma unroll
          for (int j = 0; j < 4; ++j) {
            int srow = wm + mb * 16 + r4 + j;
            int col = wn + nb * 16 + lr;
            outq[srow * 128 + col] = f2bf(phi_f(acc[mb][nb][j]));
          }
    } else {                                // pk/v -> transposed [bh][d][s]
      __syncthreads();                      // waves done reading ldsW
      #pragma unroll
      for (int mb = 0; mb < 4; ++mb)
        #pragma unroll
        for (int nb = 0; nb < 4; ++nb)
          #pragma unroll
          for (int j = 0; j < 4; ++j) {
            int srow = wm + mb * 16 + r4 + j;
            int col = wn + nb * 16 + lr;
            float v0 = acc[mb][nb][j];
            if (wsel == 1) v0 = phi_f(v0);
            ldsW[srow * 128 + (col ^ ((srow & 63) << 1))] = f2bf(v0);
          }
      __syncthreads();
      const int dc = t >> 1, sh = (t & 1) * 64;
      u16* outT = (wsel == 1 ? pkT : vT) + (size_t)bh * 262144 + (size_t)dc * 2048 + sl0 + sh;
      for (int g = 0; g < 8; ++g) {
        u16x8 buf;
        #pragma unroll
        for (int e = 0; e < 8; ++e) {
          int s = sh + g * 8 + e;
          buf[e] = ldsW[s * 128 + (dc ^ ((s & 63) << 1))];
        }
        *(u16x8*)(outT + g * 8) = buf;
      }
    }
  }
}

// ---------------- K2: kv partials = pk^T v ----------------
__global__ __launch_bounds__(256) void mla_kv(
    const u16* __restrict__ pkT, const u16* __restrict__ vT, float* __restrict__ kvp) {
  __shared__ u16 ldsA[128 * 32];
  __shared__ u16 ldsB[128 * 32];
  const int t = threadIdx.x;
  const int bh = blockIdx.x, part = blockIdx.y;
  const int s0 = part * 512;
  const u16* Ag = pkT + (size_t)bh * 262144;
  const u16* Bg = vT + (size_t)bh * 262144;
  const int wave = t >> 6, lane = t & 63;
  const int wm = (wave >> 1) * 64, wn = (wave & 1) * 64;
  const int lr = lane & 15, lk = (lane >> 4) * 8, r4 = (lane >> 4) * 4;
  f32x4 acc[4][4];
  #pragma unroll
  for (int mb = 0; mb < 4; ++mb)
    #pragma unroll
    for (int nb = 0; nb < 4; ++nb) acc[mb][nb] = (f32x4)0.f;
  for (int ks = 0; ks < 16; ++ks) {
    __syncthreads();
    const int sc = s0 + ks * 32;
    #pragma unroll
    for (int i = 0; i < 2; ++i) {
      int row = i * 64 + (t >> 2);
      gload16(Ag + (size_t)row * 2048 + sc + (t & 3) * 8, &ldsA[i * 2048 + t * 8]);
      gload16(Bg + (size_t)row * 2048 + sc + (t & 3) * 8, &ldsB[i * 2048 + t * 8]);
    }
    __syncthreads();
    bf16x8 af[4], bb[4];
    #pragma unroll
    for (int mb = 0; mb < 4; ++mb)
      af[mb] = *(const bf16x8*)&ldsA[(wm + mb * 16 + lr) * 32 + lk];
    #pragma unroll
    for (int nb = 0; nb < 4; ++nb)
      bb[nb] = *(const bf16x8*)&ldsB[(wn + nb * 16 + lr) * 32 + lk];
    #pragma unroll
    for (int mb = 0; mb < 4; ++mb)
      #pragma unroll
      for (int nb = 0; nb < 4; ++nb)
        acc[mb][nb] = mfma16(af[mb], bb[nb], acc[mb][nb]);
  }
  float* op = kvp + ((size_t)part * 128 + bh) * 16384;
  #pragma unroll
  for (int mb = 0; mb < 4; ++mb)
    #pragma unroll
    for (int nb = 0; nb < 4; ++nb)
      #pragma unroll
      for (int j = 0; j < 4; ++j)
        op[(wm + mb * 16 + r4 + j) * 128 + wn + nb * 16 + lr] = acc[mb][nb][j];
}

// ---------------- K2b: sum partials, write kv^T bf16 ----------------
__global__ __launch_bounds__(256) void mla_kvreduce(const float* __restrict__ kvp,
                                                    u16* __restrict__ kvT) {
  __shared__ float lds[128 * 128];   // XOR-swizzled for the column read
  const int t = threadIdx.x, bh = blockIdx.x;
  for (int idx = t; idx < 16384; idx += 256) {
    float s = 0.f;
    #pragma unroll
    for (int p = 0; p < 4; ++p) s += kvp[((size_t)p * 128 + bh) * 16384 + idx];
    int d = idx >> 7, e = idx & 127;
    lds[d * 128 + (e ^ d)] = s;
  }
  __syncthreads();
  const int e = t >> 1, half = (t & 1) * 64;
  u16* op = kvT + (size_t)bh * 16384 + e * 128 + half;
  for (int g = 0; g < 8; ++g) {
    u16x8 buf;
    #pragma unroll
    for (int j = 0; j < 8; ++j) {
      int d = half + g * 8 + j;
      buf[j] = f2bf(lds[d * 128 + (e ^ d)]);
    }
    *(u16x8*)(op + g * 8) = buf;
  }
}

// ---------------- K2c: ksum[bh][d] = sum_s pk[s][d] ----------------
__global__ __launch_bounds__(256) void mla_ksum(const u16* __restrict__ pkT,
                                                float* __restrict__ ksum) {
  const int t = threadIdx.x, lane = t & 63, wave = t >> 6;
  const int gw = blockIdx.x * 4 + wave;    // 0..16383 = bh*128 + d
  const u16* row = pkT + (size_t)gw * 2048;
  float s = 0.f;
  #pragma unroll
  for (int g = 0; g < 4; ++g) {
    u16x8 v = *(const u16x8*)&row[g * 512 + lane * 8];
    #pragma unroll
    for (int j = 0; j < 8; ++j) s += bf2f(v[j]);
  }
  #pragma unroll
  for (int off = 32; off; off >>= 1) s += __shfl_down(s, off);
  if (lane == 0) ksum[gw] = s;
}

// ---------------- K3: num = pq@kv, den = pq@ksum, ctx = num/(den+eps) --------
__global__ __launch_bounds__(256) void mla_ctx(
    const u16* __restrict__ pq, const u16* __restrict__ kvT,
    const float* __restrict__ ksum, u16* __restrict__ ctx) {
  __shared__ u16 ldsA[128 * 128];
  __shared__ float ksl[128];
  __shared__ float dls[128];
  const int t = threadIdx.x;
  const int st = blockIdx.x, bh = blockIdx.y;
  const int sl0 = st * 128;
  const u16* Ag = pq + (size_t)bh * 262144 + (size_t)sl0 * 128;
  const u16* Bg = kvT + (size_t)bh * 16384;
  #pragma unroll
  for (int i = 0; i < 8; ++i)
    gload16(Ag + i * 2048 + t * 8, &ldsA[i * 2048 + t * 8]);
  if (t < 128) ksl[t] = ksum[bh * 128 + t];
  __syncthreads();
  const int wave = t >> 6, lane = t & 63;
  const int wm = (wave >> 1) * 64, wn = (wave & 1) * 64;
  const int lr = lane & 15, lk = (lane >> 4) * 8, r4 = (lane >> 4) * 4;
  f32x4 acc[4][4];
  #pragma unroll
  for (int mb = 0; mb < 4; ++mb)
    #pragma unroll
    for (int nb = 0; nb < 4; ++nb) acc[mb][nb] = (f32x4)0.f;
  #pragma unroll
  for (int ks = 0; ks < 4; ++ks) {
    bf16x8 af[4], bb[4];
    #pragma unroll
    for (int mb = 0; mb < 4; ++mb)
      af[mb] = *(const bf16x8*)&ldsA[(wm + mb * 16 + lr) * 128 + ks * 32 + lk];
    #pragma unroll
    for (int nb = 0; nb < 4; ++nb)
      bb[nb] = *(const bf16x8*)(Bg + (wn + nb * 16 + lr) * 128 + ks * 32 + lk);
    #pragma unroll
    for (int mb = 0; mb < 4; ++mb)
      #pragma unroll
      for (int nb = 0; nb < 4; ++nb)
        acc[mb][nb] = mfma16(af[mb], bb[nb], acc[mb][nb]);
  }
  if (t < 128) {                           // den for this tile's 128 rows
    float s = 0.f;
    #pragma unroll
    for (int g = 0; g < 16; ++g) {
      int blk = (g + t) & 15;
      u16x8 v = *(const u16x8*)&ldsA[t * 128 + blk * 8];
      #pragma unroll
      for (int j = 0; j < 8; ++j) s += bf2f(v[j]) * ksl[blk * 8 + j];
    }
    dls[t] = s + 1e-6f;
  }
  __syncthreads();
  const int b = bh >> 4, h = bh & 15;
  u16* oc = ctx + ((size_t)b * 2048 + sl0) * 2048 + h * 128;
  #pragma unroll
  for (int mb = 0; mb < 4; ++mb)
    #pragma unroll
    for (int nb = 0; nb < 4; ++nb)
      #pragma unroll
      for (int j = 0; j < 4; ++j) {
        int srow = wm + mb * 16 + r4 + j;
        int col = wn + nb * 16 + lr;
        oc[(size_t)srow * 2048 + col] = f2bf(acc[mb][nb][j] / dls[srow]);
      }
}

// ---------------- K4: out = ctx @ Wo + bo (fp32 out) ----------------
__global__ __launch_bounds__(256) void mla_out(
    const u16* __restrict__ ctx, const u16* __restrict__ WoT,
    const float* __restrict__ bo, float* __restrict__ out) {
  __shared__ u16 ldsA[128 * 32];
  __shared__ u16 ldsB[128 * 32];
  __shared__ float bol[128];
  const int t = threadIdx.x;
  const int mt = (int)blockIdx.x >> 4, nt = (int)blockIdx.x & 15;
  if (t < 128) bol[t] = bo[nt * 128 + t];
  const u16* Ag = ctx + (size_t)mt * 128 * 2048;
  const u16* Bg = WoT + (size_t)nt * 128 * 2048;
  const int wave = t >> 6, lane = t & 63;
  const int wm = (wave >> 1) * 64, wn = (wave & 1) * 64;
  const int lr = lane & 15, lk = (lane >> 4) * 8, r4 = (lane >> 4) * 4;
  f32x4 acc[4][4];
  #pragma unroll
  for (int mb = 0; mb < 4; ++mb)
    #pragma unroll
    for (int nb = 0; nb < 4; ++nb) acc[mb][nb] = (f32x4)0.f;
  for (int ks = 0; ks < 64; ++ks) {
    __syncthreads();
    const int kc = ks * 32;
    #pragma unroll
    for (int i = 0; i < 2; ++i) {
      int row = i * 64 + (t >> 2);
      gload16(Ag + (size_t)row * 2048 + kc + (t & 3) * 8, &ldsA[i * 2048 + t * 8]);
      gload16(Bg + (size_t)row * 2048 + kc + (t & 3) * 8, &ldsB[i * 2048 + t * 8]);
    }
    __syncthreads();
    bf16x8 af[4], bb[4];
    #pragma unroll
    for (int mb = 0; mb < 4; ++mb)
      af[mb] = *(const bf16x8*)&ldsA[(wm + mb * 16 + lr) * 32 + lk];
    #pragma unroll
    for (int nb = 0; nb < 4; ++nb)
      bb[nb] = *(const bf16x8*)&ldsB[(wn + nb * 16 + lr) * 32 + lk];
    #pragma unroll
    for (int mb = 0; mb < 4; ++mb)
      #pragma unroll
      for (int nb = 0; nb < 4; ++nb)
        acc[mb][nb] = mfma16(af[mb], bb[nb], acc[mb][nb]);
  }
  float* og = out + (size_t)mt * 128 * 2048 + nt * 128;
  #pragma unroll
  for (int mb = 0; mb < 4; ++mb)
    #pragma unroll
    for (int nb = 0; nb < 4; ++nb)
      #pragma unroll
      for (int j = 0; j < 4; ++j) {
        int srow = wm + mb * 16 + r4 + j;
        int col = wn + nb * 16 + lr;
        og[(size_t)srow * 2048 + col] = acc[mb][nb][j] + bol[col];
      }
}

extern "C" void kernel_launch(void* const* d_in, const int* in_sizes, int n_in,
                              void* d_out, int out_size, void* d_ws, size_t ws_size,
                              hipStream_t stream) {
  (void)in_sizes; (void)n_in; (void)out_size;
  const float* X  = (const float*)d_in[0];
  const float* Wq = (const float*)d_in[1];
  const float* Wk = (const float*)d_in[2];
  const float* Wv = (const float*)d_in[3];
  const float* Wo = (const float*)d_in[4];
  const float* bo = (const float*)d_in[5];
  float* out = (float*)d_out;
  char* ws = (char*)d_ws;
  if (ws_size < WS_NEED) return;   // visible failure if workspace too small

  u16*   wqT  = (u16*)(ws + OFF_WQT);
  u16*   wkT  = (u16*)(ws + OFF_WKT);
  u16*   wvT  = (u16*)(ws + OFF_WVT);
  u16*   woT  = (u16*)(ws + OFF_WOT);
  u16*   pq   = (u16*)(ws + OFF_PQ);
  u16*   pkT  = (u16*)(ws + OFF_PKT);
  u16*   vT   = (u16*)(ws + OFF_VT);
  float* kvp  = (float*)(ws + OFF_KVP);
  u16*   kvT  = (u16*)(ws + OFF_KVT);
  float* ksum = (float*)(ws + OFF_KSUM);
  u16*   ctx  = (u16*)(ws + OFF_CTX);

  dim3 tb(32, 8);
  mla_transpose_cvt<<<dim3(4, 4, 16), tb, 0, stream>>>(Wq, wqT, 128);
  mla_transpose_cvt<<<dim3(4, 4, 16), tb, 0, stream>>>(Wk, wkT, 128);
  mla_transpose_cvt<<<dim3(4, 4, 16), tb, 0, stream>>>(Wv, wvT, 128);
  mla_transpose_cvt<<<dim3(64, 64, 1), tb, 0, stream>>>(Wo, woT, 2048);
  mla_qkv<<<dim3(128, 16), 256, 0, stream>>>(X, wqT, wkT, wvT, pq, pkT, vT);
  mla_kv<<<dim3(128, 4), 256, 0, stream>>>(pkT, vT, kvp);
  mla_kvreduce<<<128, 256, 0, stream>>>(kvp, kvT);
  mla_ksum<<<4096, 256, 0, stream>>>(pkT, ksum);
  mla_ctx<<<dim3(16, 128), 256, 0, stream>>>(pq, kvT, ksum, ctx);
  mla_out<<<2048, 256, 0, stream>>>(ctx, woT, bo, out);
}

// Round 3
// 430.985 us; speedup vs baseline: 1.0966x; 1.0966x over previous
//
#include <hip/hip_runtime.h>
#include <stdint.h>

typedef unsigned short u16;
typedef __attribute__((ext_vector_type(4))) float f32x4;
typedef __attribute__((ext_vector_type(8))) __bf16 bf16x8;
typedef __attribute__((ext_vector_type(8))) u16 u16x8;

#define AS1 __attribute__((address_space(1)))
#define AS3 __attribute__((address_space(3)))

// async global->LDS, 16B per lane. LDS dest must be linear in lane id
// (wave-uniform base + lane*16).
__device__ __forceinline__ void gload16(const void* g, void* l) {
  __builtin_amdgcn_global_load_lds((const AS1 void*)g, (AS3 void*)l, 16, 0, 0);
}

__device__ __forceinline__ float bf2f(u16 u) {
  union { uint32_t i; float f; } v; v.i = ((uint32_t)u) << 16; return v.f;
}
__device__ __forceinline__ u16 f2bf(float f) {  // RTNE, matches numpy/jax
  uint32_t x = __builtin_bit_cast(uint32_t, f);
  x += 0x7fffu + ((x >> 16) & 1u);
  return (u16)(x >> 16);
}
__device__ __forceinline__ float phi_f(float x) { return x > 0.f ? x + 1.f : __expf(x); }

__device__ __forceinline__ f32x4 mfma16(bf16x8 a, bf16x8 b, f32x4 c) {
  return __builtin_amdgcn_mfma_f32_16x16x32_bf16(a, b, c, 0, 0, 0);
}

// ---------------- workspace layout (bytes) — total 249,102,336 (r2 ran) -------
#define OFF_WQT  0ULL
#define OFF_WKT  (OFF_WQT + 524288ULL)
#define OFF_WVT  (OFF_WKT + 524288ULL)
#define OFF_WOT  (OFF_WVT + 524288ULL)           // 2048*2048*2 bf16
#define OFF_PQ   (OFF_WOT + 8388608ULL)          // [128 bh][2048 s][128 d] bf16
#define OFF_PKT  (OFF_PQ  + 67108864ULL)         // [128 bh][128 d][2048 s] bf16
#define OFF_VT   (OFF_PKT + 67108864ULL)         // [128 bh][128 d][2048 s] bf16
#define OFF_KVP  (OFF_VT  + 67108864ULL)         // [4 part][128 bh][128 e][128 d] f32
#define OFF_KVT  (OFF_KVP + 33554432ULL)         // [128 bh][128 e][128 d] bf16 (kv^T)
#define OFF_KSUM (OFF_KVT + 4194304ULL)          // [128 bh][128] f32
#define OFF_CTX  OFF_PKT                          // alias: pkT dead after mla_ksum
#define WS_NEED  (OFF_KSUM + 65536ULL)

// ---------------- batched square transpose + fp32->bf16 convert ----------------
__global__ __launch_bounds__(256) void mla_transpose_cvt(const float* __restrict__ src,
                                                         u16* __restrict__ dst, int n) {
  __shared__ u16 tile[32][33];
  const int b = blockIdx.z;
  const float* s = src + (size_t)b * n * n;
  u16* d = dst + (size_t)b * n * n;
  const int x = blockIdx.x * 32 + threadIdx.x;
  const int y0 = blockIdx.y * 32 + threadIdx.y;
  #pragma unroll
  for (int i = 0; i < 32; i += 8)
    tile[threadIdx.y + i][threadIdx.x] = f2bf(s[(size_t)(y0 + i) * n + x]);
  __syncthreads();
  const int x2 = blockIdx.y * 32 + threadIdx.x;
  const int y2 = blockIdx.x * 32 + threadIdx.y;
  #pragma unroll
  for (int i = 0; i < 32; i += 8)
    d[(size_t)(y2 + i) * n + x2] = tile[threadIdx.x][threadIdx.y + i];
}

// ---------------- K1: q/k/v projections + phi ----------------
// grid (128 row-tiles, 16 heads), 256 thr. pq written [s][d] (A=X,B=W^T);
// pk/v written ALREADY-TRANSPOSED [d][s] by swapping MFMA operand roles
// (A=W^T rows -> m=d, B=X rows -> n=s). No LDS transpose epilogue.
__global__ __launch_bounds__(256) void mla_qkv(
    const float* __restrict__ X, const u16* __restrict__ WqT,
    const u16* __restrict__ WkT, const u16* __restrict__ WvT,
    u16* __restrict__ pq, u16* __restrict__ pkT, u16* __restrict__ vT) {
  __shared__ u16 ldsX[128 * 128];
  __shared__ u16 ldsW[128 * 128];
  const int t = threadIdx.x;
  const int rt = blockIdx.x, h = blockIdx.y;
  const int r0 = rt * 128;
  const int b = r0 >> 11;
  const int sl0 = r0 & 2047;
  const int bh = b * 16 + h;
  const u16* Wsrc[3] = { WqT + h * 16384, WkT + h * 16384, WvT + h * 16384 };

  // issue W0 staging first so HBM latency hides under the X conversion
  #pragma unroll
  for (int i = 0; i < 8; ++i)
    gload16(Wsrc[0] + i * 2048 + t * 8, &ldsW[i * 2048 + t * 8]);

  // reg-stage X: fp32 global -> cvt -> bf16 LDS (row-major 128x128)
  const float* Xg = X + (size_t)r0 * 2048 + h * 128;
  #pragma unroll
  for (int j = 0; j < 8; ++j) {
    int e = j * 2048 + t * 8;
    int row = e >> 7, col = e & 127;
    const float* p = Xg + (size_t)row * 2048 + col;
    f32x4 a = *(const f32x4*)p;
    f32x4 c = *(const f32x4*)(p + 4);
    u16x8 wv;
    #pragma unroll
    for (int q = 0; q < 4; ++q) { wv[q] = f2bf(a[q]); wv[4 + q] = f2bf(c[q]); }
    *(u16x8*)&ldsX[e] = wv;
  }
  __syncthreads();   // X writes visible; W0 gload drained

  const int wave = t >> 6, lane = t & 63;
  const int wm = (wave >> 1) * 64, wn = (wave & 1) * 64;
  const int lr = lane & 15, lk = (lane >> 4) * 8, r4 = (lane >> 4) * 4;

  for (int wsel = 0; wsel < 3; ++wsel) {
    if (wsel) {
      __syncthreads();                     // everyone done reading previous ldsW
      #pragma unroll
      for (int i = 0; i < 8; ++i)
        gload16(Wsrc[wsel] + i * 2048 + t * 8, &ldsW[i * 2048 + t * 8]);
      __syncthreads();                     // staged (drains vmcnt)
    }
    f32x4 acc[4][4];
    #pragma unroll
    for (int mb = 0; mb < 4; ++mb)
      #pragma unroll
      for (int nb = 0; nb < 4; ++nb) acc[mb][nb] = (f32x4)0.f;

    if (wsel == 0) {
      // q: A = X rows (m=s), B = W^T rows (n=d) -> D[s][d]
      #pragma unroll
      for (int ks = 0; ks < 4; ++ks) {
        bf16x8 af[4], bb[4];
        #pragma unroll
        for (int mb = 0; mb < 4; ++mb)
          af[mb] = *(const bf16x8*)&ldsX[(wm + mb * 16 + lr) * 128 + ks * 32 + lk];
        #pragma unroll
        for (int nb = 0; nb < 4; ++nb)
          bb[nb] = *(const bf16x8*)&ldsW[(wn + nb * 16 + lr) * 128 + ks * 32 + lk];
        #pragma unroll
        for (int mb = 0; mb < 4; ++mb)
          #pragma unroll
          for (int nb = 0; nb < 4; ++nb)
            acc[mb][nb] = mfma16(af[mb], bb[nb], acc[mb][nb]);
      }
      u16* outq = pq + (size_t)bh * 262144 + (size_t)sl0 * 128;
      #pragma unroll
      for (int mb = 0; mb < 4; ++mb)
        #pragma unroll
        for (int nb = 0; nb < 4; ++nb)
          #pragma unroll
          for (int j = 0; j < 4; ++j) {
            int srow = wm + mb * 16 + r4 + j;
            int col = wn + nb * 16 + lr;
            outq[srow * 128 + col] = f2bf(phi_f(acc[mb][nb][j]));
          }
    } else {
      // k/v: A = W^T rows (m=d), B = X rows (n=s) -> D[d][s], store transposed
      #pragma unroll
      for (int ks = 0; ks < 4; ++ks) {
        bf16x8 af[4], bb[4];
        #pragma unroll
        for (int mb = 0; mb < 4; ++mb)
          af[mb] = *(const bf16x8*)&ldsW[(wm + mb * 16 + lr) * 128 + ks * 32 + lk];
        #pragma unroll
        for (int nb = 0; nb < 4; ++nb)
          bb[nb] = *(const bf16x8*)&ldsX[(wn + nb * 16 + lr) * 128 + ks * 32 + lk];
        #pragma unroll
        for (int mb = 0; mb < 4; ++mb)
          #pragma unroll
          for (int nb = 0; nb < 4; ++nb)
            acc[mb][nb] = mfma16(af[mb], bb[nb], acc[mb][nb]);
      }
      u16* outT = (wsel == 1 ? pkT : vT) + (size_t)bh * 262144 + sl0;
      if (wsel == 1) {
        #pragma unroll
        for (int mb = 0; mb < 4; ++mb)
          #pragma unroll
          for (int nb = 0; nb < 4; ++nb)
            #pragma unroll
            for (int j = 0; j < 4; ++j) {
              int drow = wm + mb * 16 + r4 + j;
              int scol = wn + nb * 16 + lr;
              outT[(size_t)drow * 2048 + scol] = f2bf(phi_f(acc[mb][nb][j]));
            }
      } else {
        #pragma unroll
        for (int mb = 0; mb < 4; ++mb)
          #pragma unroll
          for (int nb = 0; nb < 4; ++nb)
            #pragma unroll
            for (int j = 0; j < 4; ++j) {
              int drow = wm + mb * 16 + r4 + j;
              int scol = wn + nb * 16 + lr;
              outT[(size_t)drow * 2048 + scol] = f2bf(acc[mb][nb][j]);
            }
      }
    }
  }
}

// ---------------- K2: kv^T partials = (v^T)(pk^T)^T per (bh, s-partition) -----
// A = v rows (m=e), B = pk rows (n=d) -> D[e][d] = sum_s v[s][e] pk[s][d] = kv^T
__global__ __launch_bounds__(256) void mla_kv(
    const u16* __restrict__ pkT, const u16* __restrict__ vT, float* __restrict__ kvp) {
  __shared__ u16 ldsA[128 * 32];   // pk tile [d][32 s]
  __shared__ u16 ldsB[128 * 32];   // v  tile [e][32 s]
  const int t = threadIdx.x;
  const int bh = blockIdx.x, part = blockIdx.y;
  const int s0 = part * 512;
  const u16* Ag = pkT + (size_t)bh * 262144;
  const u16* Bg = vT + (size_t)bh * 262144;
  const int wave = t >> 6, lane = t & 63;
  const int wm = (wave >> 1) * 64, wn = (wave & 1) * 64;
  const int lr = lane & 15, lk = (lane >> 4) * 8, r4 = (lane >> 4) * 4;
  f32x4 acc[4][4];
  #pragma unroll
  for (int mb = 0; mb < 4; ++mb)
    #pragma unroll
    for (int nb = 0; nb < 4; ++nb) acc[mb][nb] = (f32x4)0.f;
  for (int ks = 0; ks < 16; ++ks) {
    __syncthreads();
    const int sc = s0 + ks * 32;
    #pragma unroll
    for (int i = 0; i < 2; ++i) {
      int row = i * 64 + (t >> 2);
      gload16(Ag + (size_t)row * 2048 + sc + (t & 3) * 8, &ldsA[i * 2048 + t * 8]);
      gload16(Bg + (size_t)row * 2048 + sc + (t & 3) * 8, &ldsB[i * 2048 + t * 8]);
    }
    __syncthreads();
    bf16x8 af[4], bb[4];
    #pragma unroll
    for (int mb = 0; mb < 4; ++mb)
      af[mb] = *(const bf16x8*)&ldsB[(wm + mb * 16 + lr) * 32 + lk];   // v: m=e
    #pragma unroll
    for (int nb = 0; nb < 4; ++nb)
      bb[nb] = *(const bf16x8*)&ldsA[(wn + nb * 16 + lr) * 32 + lk];   // pk: n=d
    #pragma unroll
    for (int mb = 0; mb < 4; ++mb)
      #pragma unroll
      for (int nb = 0; nb < 4; ++nb)
        acc[mb][nb] = mfma16(af[mb], bb[nb], acc[mb][nb]);
  }
  float* op = kvp + ((size_t)part * 128 + bh) * 16384;   // [e][d]
  #pragma unroll
  for (int mb = 0; mb < 4; ++mb)
    #pragma unroll
    for (int nb = 0; nb < 4; ++nb)
      #pragma unroll
      for (int j = 0; j < 4; ++j)
        op[(wm + mb * 16 + r4 + j) * 128 + wn + nb * 16 + lr] = acc[mb][nb][j];
}

// ---------------- K2b: elementwise reduce of 4 partials -> kv^T bf16 ----------
__global__ __launch_bounds__(256) void mla_kvreduce(const float* __restrict__ kvp,
                                                    u16* __restrict__ kvT) {
  const size_t i0 = ((size_t)blockIdx.x * 256 + threadIdx.x) * 8;  // over 2,097,152
  f32x4 lo = (f32x4)0.f, hi = (f32x4)0.f;
  #pragma unroll
  for (int p = 0; p < 4; ++p) {
    const float* src = kvp + (size_t)p * 2097152 + i0;
    lo += *(const f32x4*)src;
    hi += *(const f32x4*)(src + 4);
  }
  u16x8 o;
  #pragma unroll
  for (int j = 0; j < 4; ++j) { o[j] = f2bf(lo[j]); o[4 + j] = f2bf(hi[j]); }
  *(u16x8*)(kvT + i0) = o;
}

// ---------------- K2c: ksum[bh][d] = sum_s pk[s][d] (one wave per pkT row) ----
__global__ __launch_bounds__(256) void mla_ksum(const u16* __restrict__ pkT,
                                                float* __restrict__ ksum) {
  const int t = threadIdx.x, lane = t & 63, wave = t >> 6;
  const int gw = blockIdx.x * 4 + wave;    // 0..16383 = bh*128 + d
  const u16* row = pkT + (size_t)gw * 2048;
  float s = 0.f;
  #pragma unroll
  for (int g = 0; g < 4; ++g) {
    u16x8 v = *(const u16x8*)&row[g * 512 + lane * 8];
    #pragma unroll
    for (int j = 0; j < 8; ++j) s += bf2f(v[j]);
  }
  #pragma unroll
  for (int off = 32; off; off >>= 1) s += __shfl_down(s, off);
  if (lane == 0) ksum[gw] = s;
}

// ---------------- K3: num = pq@kv, den = pq@ksum, ctx = num/(den+eps) --------
__global__ __launch_bounds__(256) void mla_ctx(
    const u16* __restrict__ pq, const u16* __restrict__ kvT,
    const float* __restrict__ ksum, u16* __restrict__ ctx) {
  __shared__ u16 ldsA[128 * 128];
  __shared__ float ksl[128];
  __shared__ float dls[128];
  const int t = threadIdx.x;
  const int st = blockIdx.x, bh = blockIdx.y;
  const int sl0 = st * 128;
  const u16* Ag = pq + (size_t)bh * 262144 + (size_t)sl0 * 128;
  const u16* Bg = kvT + (size_t)bh * 16384;
  #pragma unroll
  for (int i = 0; i < 8; ++i)
    gload16(Ag + i * 2048 + t * 8, &ldsA[i * 2048 + t * 8]);
  if (t < 128) ksl[t] = ksum[bh * 128 + t];
  __syncthreads();
  const int wave = t >> 6, lane = t & 63;
  const int wm = (wave >> 1) * 64, wn = (wave & 1) * 64;
  const int lr = lane & 15, lk = (lane >> 4) * 8, r4 = (lane >> 4) * 4;
  f32x4 acc[4][4];
  #pragma unroll
  for (int mb = 0; mb < 4; ++mb)
    #pragma unroll
    for (int nb = 0; nb < 4; ++nb) acc[mb][nb] = (f32x4)0.f;
  #pragma unroll
  for (int ks = 0; ks < 4; ++ks) {
    bf16x8 af[4], bb[4];
    #pragma unroll
    for (int mb = 0; mb < 4; ++mb)
      af[mb] = *(const bf16x8*)&ldsA[(wm + mb * 16 + lr) * 128 + ks * 32 + lk];
    #pragma unroll
    for (int nb = 0; nb < 4; ++nb)
      bb[nb] = *(const bf16x8*)(Bg + (wn + nb * 16 + lr) * 128 + ks * 32 + lk);
    #pragma unroll
    for (int mb = 0; mb < 4; ++mb)
      #pragma unroll
      for (int nb = 0; nb < 4; ++nb)
        acc[mb][nb] = mfma16(af[mb], bb[nb], acc[mb][nb]);
  }
  if (t < 128) {                           // den for this tile's 128 rows
    float s = 0.f;
    #pragma unroll
    for (int g = 0; g < 16; ++g) {
      int blk = (g + t) & 15;
      u16x8 v = *(const u16x8*)&ldsA[t * 128 + blk * 8];
      #pragma unroll
      for (int j = 0; j < 8; ++j) s += bf2f(v[j]) * ksl[blk * 8 + j];
    }
    dls[t] = s + 1e-6f;
  }
  __syncthreads();
  const int b = bh >> 4, h = bh & 15;
  u16* oc = ctx + ((size_t)b * 2048 + sl0) * 2048 + h * 128;
  #pragma unroll
  for (int mb = 0; mb < 4; ++mb)
    #pragma unroll
    for (int nb = 0; nb < 4; ++nb)
      #pragma unroll
      for (int j = 0; j < 4; ++j) {
        int srow = wm + mb * 16 + r4 + j;
        int col = wn + nb * 16 + lr;
        oc[(size_t)srow * 2048 + col] = f2bf(acc[mb][nb][j] / dls[srow]);
      }
}

// ---------------- K4: out = ctx @ Wo + bo (fp32 out) ----------------
__global__ __launch_bounds__(256) void mla_out(
    const u16* __restrict__ ctx, const u16* __restrict__ WoT,
    const float* __restrict__ bo, float* __restrict__ out) {
  __shared__ u16 ldsA[128 * 32];
  __shared__ u16 ldsB[128 * 32];
  __shared__ float bol[128];
  const int t = threadIdx.x;
  const int mt = (int)blockIdx.x >> 4, nt = (int)blockIdx.x & 15;
  if (t < 128) bol[t] = bo[nt * 128 + t];
  const u16* Ag = ctx + (size_t)mt * 128 * 2048;
  const u16* Bg = WoT + (size_t)nt * 128 * 2048;
  const int wave = t >> 6, lane = t & 63;
  const int wm = (wave >> 1) * 64, wn = (wave & 1) * 64;
  const int lr = lane & 15, lk = (lane >> 4) * 8, r4 = (lane >> 4) * 4;
  f32x4 acc[4][4];
  #pragma unroll
  for (int mb = 0; mb < 4; ++mb)
    #pragma unroll
    for (int nb = 0; nb < 4; ++nb) acc[mb][nb] = (f32x4)0.f;
  for (int ks = 0; ks < 64; ++ks) {
    __syncthreads();
    const int kc = ks * 32;
    #pragma unroll
    for (int i = 0; i < 2; ++i) {
      int row = i * 64 + (t >> 2);
      gload16(Ag + (size_t)row * 2048 + kc + (t & 3) * 8, &ldsA[i * 2048 + t * 8]);
      gload16(Bg + (size_t)row * 2048 + kc + (t & 3) * 8, &ldsB[i * 2048 + t * 8]);
    }
    __syncthreads();
    bf16x8 af[4], bb[4];
    #pragma unroll
    for (int mb = 0; mb < 4; ++mb)
      af[mb] = *(const bf16x8*)&ldsA[(wm + mb * 16 + lr) * 32 + lk];
    #pragma unroll
    for (int nb = 0; nb < 4; ++nb)
      bb[nb] = *(const bf16x8*)&ldsB[(wn + nb * 16 + lr) * 32 + lk];
    #pragma unroll
    for (int mb = 0; mb < 4; ++mb)
      #pragma unroll
      for (int nb = 0; nb < 4; ++nb)
        acc[mb][nb] = mfma16(af[mb], bb[nb], acc[mb][nb]);
  }
  float* og = out + (size_t)mt * 128 * 2048 + nt * 128;
  #pragma unroll
  for (int mb = 0; mb < 4; ++mb)
    #pragma unroll
    for (int nb = 0; nb < 4; ++nb)
      #pragma unroll
      for (int j = 0; j < 4; ++j) {
        int srow = wm + mb * 16 + r4 + j;
        int col = wn + nb * 16 + lr;
        og[(size_t)srow * 2048 + col] = acc[mb][nb][j] + bol[col];
      }
}

extern "C" void kernel_launch(void* const* d_in, const int* in_sizes, int n_in,
                              void* d_out, int out_size, void* d_ws, size_t ws_size,
                              hipStream_t stream) {
  (void)in_sizes; (void)n_in; (void)out_size;
  const float* X  = (const float*)d_in[0];
  const float* Wq = (const float*)d_in[1];
  const float* Wk = (const float*)d_in[2];
  const float* Wv = (const float*)d_in[3];
  const float* Wo = (const float*)d_in[4];
  const float* bo = (const float*)d_in[5];
  float* out = (float*)d_out;
  char* ws = (char*)d_ws;
  if (ws_size < WS_NEED) return;   // visible failure if workspace too small

  u16*   wqT  = (u16*)(ws + OFF_WQT);
  u16*   wkT  = (u16*)(ws + OFF_WKT);
  u16*   wvT  = (u16*)(ws + OFF_WVT);
  u16*   woT  = (u16*)(ws + OFF_WOT);
  u16*   pq   = (u16*)(ws + OFF_PQ);
  u16*   pkT  = (u16*)(ws + OFF_PKT);
  u16*   vT   = (u16*)(ws + OFF_VT);
  float* kvp  = (float*)(ws + OFF_KVP);
  u16*   kvT  = (u16*)(ws + OFF_KVT);
  float* ksum = (float*)(ws + OFF_KSUM);
  u16*   ctx  = (u16*)(ws + OFF_CTX);

  dim3 tb(32, 8);
  mla_transpose_cvt<<<dim3(4, 4, 16), tb, 0, stream>>>(Wq, wqT, 128);
  mla_transpose_cvt<<<dim3(4, 4, 16), tb, 0, stream>>>(Wk, wkT, 128);
  mla_transpose_cvt<<<dim3(4, 4, 16), tb, 0, stream>>>(Wv, wvT, 128);
  mla_transpose_cvt<<<dim3(64, 64, 1), tb, 0, stream>>>(Wo, woT, 2048);
  mla_qkv<<<dim3(128, 16), 256, 0, stream>>>(X, wqT, wkT, wvT, pq, pkT, vT);
  mla_kv<<<dim3(128, 4), 256, 0, stream>>>(pkT, vT, kvp);
  mla_kvreduce<<<1024, 256, 0, stream>>>(kvp, kvT);
  mla_ksum<<<4096, 256, 0, stream>>>(pkT, ksum);
  mla_ctx<<<dim3(16, 128), 256, 0, stream>>>(pq, kvT, ksum, ctx);
  mla_out<<<2048, 256, 0, stream>>>(ctx, woT, bo, out);
}

// Round 4
// 423.385 us; speedup vs baseline: 1.1163x; 1.0179x over previous
//
#include <hip/hip_runtime.h>
#include <stdint.h>

typedef unsigned short u16;
typedef __attribute__((ext_vector_type(4))) float f32x4;
typedef __attribute__((ext_vector_type(8))) __bf16 bf16x8;
typedef __attribute__((ext_vector_type(8))) u16 u16x8;

#define AS1 __attribute__((address_space(1)))
#define AS3 __attribute__((address_space(3)))

// async global->LDS, 16B per lane. LDS dest must be linear in lane id
// (wave-uniform base + lane*16).
__device__ __forceinline__ void gload16(const void* g, void* l) {
  __builtin_amdgcn_global_load_lds((const AS1 void*)g, (AS3 void*)l, 16, 0, 0);
}

__device__ __forceinline__ float bf2f(u16 u) {
  union { uint32_t i; float f; } v; v.i = ((uint32_t)u) << 16; return v.f;
}
__device__ __forceinline__ u16 f2bf(float f) {  // RTNE, matches numpy/jax
  uint32_t x = __builtin_bit_cast(uint32_t, f);
  x += 0x7fffu + ((x >> 16) & 1u);
  return (u16)(x >> 16);
}
__device__ __forceinline__ float phi_f(float x) { return x > 0.f ? x + 1.f : __expf(x); }

__device__ __forceinline__ f32x4 mfma16(bf16x8 a, bf16x8 b, f32x4 c) {
  return __builtin_amdgcn_mfma_f32_16x16x32_bf16(a, b, c, 0, 0, 0);
}

// ---------------- workspace layout (bytes) — total 249,102,336 (r2/r3 ran) ----
#define OFF_WQT  0ULL
#define OFF_WKT  (OFF_WQT + 524288ULL)
#define OFF_WVT  (OFF_WKT + 524288ULL)
#define OFF_WOT  (OFF_WVT + 524288ULL)           // 2048*2048*2 bf16
#define OFF_PQ   (OFF_WOT + 8388608ULL)          // [128 bh][2048 s][128 d] bf16
#define OFF_PKT  (OFF_PQ  + 67108864ULL)         // [128 bh][128 d][2048 s] bf16
#define OFF_VT   (OFF_PKT + 67108864ULL)         // [128 bh][128 d][2048 s] bf16
#define OFF_KVP  (OFF_VT  + 67108864ULL)         // [4 part][128 bh][128 e][128 d] f32
#define OFF_KVT  (OFF_KVP + 33554432ULL)         // [128 bh][128 e][128 d] bf16 (kv^T)
#define OFF_KSUM (OFF_KVT + 4194304ULL)          // [128 bh][128] f32
#define OFF_CTX  OFF_PKT                          // alias: pkT dead after mla_ksum
#define WS_NEED  (OFF_KSUM + 65536ULL)

// ---------------- batched square transpose + fp32->bf16 convert ----------------
__global__ __launch_bounds__(256) void mla_transpose_cvt(const float* __restrict__ src,
                                                         u16* __restrict__ dst, int n) {
  __shared__ u16 tile[32][33];
  const int b = blockIdx.z;
  const float* s = src + (size_t)b * n * n;
  u16* d = dst + (size_t)b * n * n;
  const int x = blockIdx.x * 32 + threadIdx.x;
  const int y0 = blockIdx.y * 32 + threadIdx.y;
  #pragma unroll
  for (int i = 0; i < 32; i += 8)
    tile[threadIdx.y + i][threadIdx.x] = f2bf(s[(size_t)(y0 + i) * n + x]);
  __syncthreads();
  const int x2 = blockIdx.y * 32 + threadIdx.x;
  const int y2 = blockIdx.x * 32 + threadIdx.y;
  #pragma unroll
  for (int i = 0; i < 32; i += 8)
    d[(size_t)(y2 + i) * n + x2] = tile[threadIdx.x][threadIdx.y + i];
}

// ---------------- K1: q/k/v projections + phi ----------------
__global__ __launch_bounds__(256) void mla_qkv(
    const float* __restrict__ X, const u16* __restrict__ WqT,
    const u16* __restrict__ WkT, const u16* __restrict__ WvT,
    u16* __restrict__ pq, u16* __restrict__ pkT, u16* __restrict__ vT) {
  __shared__ u16 ldsX[128 * 128];
  __shared__ u16 ldsW[128 * 128];
  const int t = threadIdx.x;
  const int rt = blockIdx.x, h = blockIdx.y;
  const int r0 = rt * 128;
  const int b = r0 >> 11;
  const int sl0 = r0 & 2047;
  const int bh = b * 16 + h;
  const u16* Wsrc[3] = { WqT + h * 16384, WkT + h * 16384, WvT + h * 16384 };

  #pragma unroll
  for (int i = 0; i < 8; ++i)
    gload16(Wsrc[0] + i * 2048 + t * 8, &ldsW[i * 2048 + t * 8]);

  const float* Xg = X + (size_t)r0 * 2048 + h * 128;
  #pragma unroll
  for (int j = 0; j < 8; ++j) {
    int e = j * 2048 + t * 8;
    int row = e >> 7, col = e & 127;
    const float* p = Xg + (size_t)row * 2048 + col;
    f32x4 a = *(const f32x4*)p;
    f32x4 c = *(const f32x4*)(p + 4);
    u16x8 wv;
    #pragma unroll
    for (int q = 0; q < 4; ++q) { wv[q] = f2bf(a[q]); wv[4 + q] = f2bf(c[q]); }
    *(u16x8*)&ldsX[e] = wv;
  }
  __syncthreads();

  const int wave = t >> 6, lane = t & 63;
  const int wm = (wave >> 1) * 64, wn = (wave & 1) * 64;
  const int lr = lane & 15, lk = (lane >> 4) * 8, r4 = (lane >> 4) * 4;

  for (int wsel = 0; wsel < 3; ++wsel) {
    if (wsel) {
      __syncthreads();
      #pragma unroll
      for (int i = 0; i < 8; ++i)
        gload16(Wsrc[wsel] + i * 2048 + t * 8, &ldsW[i * 2048 + t * 8]);
      __syncthreads();
    }
    f32x4 acc[4][4];
    #pragma unroll
    for (int mb = 0; mb < 4; ++mb)
      #pragma unroll
      for (int nb = 0; nb < 4; ++nb) acc[mb][nb] = (f32x4)0.f;

    if (wsel == 0) {
      #pragma unroll
      for (int ks = 0; ks < 4; ++ks) {
        bf16x8 af[4], bb[4];
        #pragma unroll
        for (int mb = 0; mb < 4; ++mb)
          af[mb] = *(const bf16x8*)&ldsX[(wm + mb * 16 + lr) * 128 + ks * 32 + lk];
        #pragma unroll
        for (int nb = 0; nb < 4; ++nb)
          bb[nb] = *(const bf16x8*)&ldsW[(wn + nb * 16 + lr) * 128 + ks * 32 + lk];
        #pragma unroll
        for (int mb = 0; mb < 4; ++mb)
          #pragma unroll
          for (int nb = 0; nb < 4; ++nb)
            acc[mb][nb] = mfma16(af[mb], bb[nb], acc[mb][nb]);
      }
      u16* outq = pq + (size_t)bh * 262144 + (size_t)sl0 * 128;
      #pragma unroll
      for (int mb = 0; mb < 4; ++mb)
        #pragma unroll
        for (int nb = 0; nb < 4; ++nb)
          #pragma unroll
          for (int j = 0; j < 4; ++j) {
            int srow = wm + mb * 16 + r4 + j;
            int col = wn + nb * 16 + lr;
            outq[srow * 128 + col] = f2bf(phi_f(acc[mb][nb][j]));
          }
    } else {
      #pragma unroll
      for (int ks = 0; ks < 4; ++ks) {
        bf16x8 af[4], bb[4];
        #pragma unroll
        for (int mb = 0; mb < 4; ++mb)
          af[mb] = *(const bf16x8*)&ldsW[(wm + mb * 16 + lr) * 128 + ks * 32 + lk];
        #pragma unroll
        for (int nb = 0; nb < 4; ++nb)
          bb[nb] = *(const bf16x8*)&ldsX[(wn + nb * 16 + lr) * 128 + ks * 32 + lk];
        #pragma unroll
        for (int mb = 0; mb < 4; ++mb)
          #pragma unroll
          for (int nb = 0; nb < 4; ++nb)
            acc[mb][nb] = mfma16(af[mb], bb[nb], acc[mb][nb]);
      }
      u16* outT = (wsel == 1 ? pkT : vT) + (size_t)bh * 262144 + sl0;
      if (wsel == 1) {
        #pragma unroll
        for (int mb = 0; mb < 4; ++mb)
          #pragma unroll
          for (int nb = 0; nb < 4; ++nb)
            #pragma unroll
            for (int j = 0; j < 4; ++j) {
              int drow = wm + mb * 16 + r4 + j;
              int scol = wn + nb * 16 + lr;
              outT[(size_t)drow * 2048 + scol] = f2bf(phi_f(acc[mb][nb][j]));
            }
      } else {
        #pragma unroll
        for (int mb = 0; mb < 4; ++mb)
          #pragma unroll
          for (int nb = 0; nb < 4; ++nb)
            #pragma unroll
            for (int j = 0; j < 4; ++j) {
              int drow = wm + mb * 16 + r4 + j;
              int scol = wn + nb * 16 + lr;
              outT[(size_t)drow * 2048 + scol] = f2bf(acc[mb][nb][j]);
            }
      }
    }
  }
}

// ---------------- K2: kv^T partials per (bh, s-partition) ----------------
__global__ __launch_bounds__(256) void mla_kv(
    const u16* __restrict__ pkT, const u16* __restrict__ vT, float* __restrict__ kvp) {
  __shared__ u16 ldsA[128 * 32];
  __shared__ u16 ldsB[128 * 32];
  const int t = threadIdx.x;
  const int bh = blockIdx.x, part = blockIdx.y;
  const int s0 = part * 512;
  const u16* Ag = pkT + (size_t)bh * 262144;
  const u16* Bg = vT + (size_t)bh * 262144;
  const int wave = t >> 6, lane = t & 63;
  const int wm = (wave >> 1) * 64, wn = (wave & 1) * 64;
  const int lr = lane & 15, lk = (lane >> 4) * 8, r4 = (lane >> 4) * 4;
  f32x4 acc[4][4];
  #pragma unroll
  for (int mb = 0; mb < 4; ++mb)
    #pragma unroll
    for (int nb = 0; nb < 4; ++nb) acc[mb][nb] = (f32x4)0.f;
  for (int ks = 0; ks < 16; ++ks) {
    __syncthreads();
    const int sc = s0 + ks * 32;
    #pragma unroll
    for (int i = 0; i < 2; ++i) {
      int row = i * 64 + (t >> 2);
      gload16(Ag + (size_t)row * 2048 + sc + (t & 3) * 8, &ldsA[i * 2048 + t * 8]);
      gload16(Bg + (size_t)row * 2048 + sc + (t & 3) * 8, &ldsB[i * 2048 + t * 8]);
    }
    __syncthreads();
    bf16x8 af[4], bb[4];
    #pragma unroll
    for (int mb = 0; mb < 4; ++mb)
      af[mb] = *(const bf16x8*)&ldsB[(wm + mb * 16 + lr) * 32 + lk];   // v: m=e
    #pragma unroll
    for (int nb = 0; nb < 4; ++nb)
      bb[nb] = *(const bf16x8*)&ldsA[(wn + nb * 16 + lr) * 32 + lk];   // pk: n=d
    #pragma unroll
    for (int mb = 0; mb < 4; ++mb)
      #pragma unroll
      for (int nb = 0; nb < 4; ++nb)
        acc[mb][nb] = mfma16(af[mb], bb[nb], acc[mb][nb]);
  }
  float* op = kvp + ((size_t)part * 128 + bh) * 16384;   // [e][d]
  #pragma unroll
  for (int mb = 0; mb < 4; ++mb)
    #pragma unroll
    for (int nb = 0; nb < 4; ++nb)
      #pragma unroll
      for (int j = 0; j < 4; ++j)
        op[(wm + mb * 16 + r4 + j) * 128 + wn + nb * 16 + lr] = acc[mb][nb][j];
}

// ---------------- K2b: elementwise reduce of 4 partials -> kv^T bf16 ----------
__global__ __launch_bounds__(256) void mla_kvreduce(const float* __restrict__ kvp,
                                                    u16* __restrict__ kvT) {
  const size_t i0 = ((size_t)blockIdx.x * 256 + threadIdx.x) * 8;
  f32x4 lo = (f32x4)0.f, hi = (f32x4)0.f;
  #pragma unroll
  for (int p = 0; p < 4; ++p) {
    const float* src = kvp + (size_t)p * 2097152 + i0;
    lo += *(const f32x4*)src;
    hi += *(const f32x4*)(src + 4);
  }
  u16x8 o;
  #pragma unroll
  for (int j = 0; j < 4; ++j) { o[j] = f2bf(lo[j]); o[4 + j] = f2bf(hi[j]); }
  *(u16x8*)(kvT + i0) = o;
}

// ---------------- K2c: ksum[bh][d] = sum_s pk[s][d] ----------------
__global__ __launch_bounds__(256) void mla_ksum(const u16* __restrict__ pkT,
                                                float* __restrict__ ksum) {
  const int t = threadIdx.x, lane = t & 63, wave = t >> 6;
  const int gw = blockIdx.x * 4 + wave;
  const u16* row = pkT + (size_t)gw * 2048;
  float s = 0.f;
  #pragma unroll
  for (int g = 0; g < 4; ++g) {
    u16x8 v = *(const u16x8*)&row[g * 512 + lane * 8];
    #pragma unroll
    for (int j = 0; j < 8; ++j) s += bf2f(v[j]);
  }
  #pragma unroll
  for (int off = 32; off; off >>= 1) s += __shfl_down(s, off);
  if (lane == 0) ksum[gw] = s;
}

// ---------------- K3: num = pq@kv, den = pq@ksum, ctx = num/(den+eps) --------
__global__ __launch_bounds__(256) void mla_ctx(
    const u16* __restrict__ pq, const u16* __restrict__ kvT,
    const float* __restrict__ ksum, u16* __restrict__ ctx) {
  __shared__ u16 ldsA[128 * 128];
  __shared__ float ksl[128];
  __shared__ float dls[128];
  const int t = threadIdx.x;
  const int st = blockIdx.x, bh = blockIdx.y;
  const int sl0 = st * 128;
  const u16* Ag = pq + (size_t)bh * 262144 + (size_t)sl0 * 128;
  const u16* Bg = kvT + (size_t)bh * 16384;
  #pragma unroll
  for (int i = 0; i < 8; ++i)
    gload16(Ag + i * 2048 + t * 8, &ldsA[i * 2048 + t * 8]);
  if (t < 128) ksl[t] = ksum[bh * 128 + t];
  __syncthreads();
  const int wave = t >> 6, lane = t & 63;
  const int wm = (wave >> 1) * 64, wn = (wave & 1) * 64;
  const int lr = lane & 15, lk = (lane >> 4) * 8, r4 = (lane >> 4) * 4;
  f32x4 acc[4][4];
  #pragma unroll
  for (int mb = 0; mb < 4; ++mb)
    #pragma unroll
    for (int nb = 0; nb < 4; ++nb) acc[mb][nb] = (f32x4)0.f;
  #pragma unroll
  for (int ks = 0; ks < 4; ++ks) {
    bf16x8 af[4], bb[4];
    #pragma unroll
    for (int mb = 0; mb < 4; ++mb)
      af[mb] = *(const bf16x8*)&ldsA[(wm + mb * 16 + lr) * 128 + ks * 32 + lk];
    #pragma unroll
    for (int nb = 0; nb < 4; ++nb)
      bb[nb] = *(const bf16x8*)(Bg + (wn + nb * 16 + lr) * 128 + ks * 32 + lk);
    #pragma unroll
    for (int mb = 0; mb < 4; ++mb)
      #pragma unroll
      for (int nb = 0; nb < 4; ++nb)
        acc[mb][nb] = mfma16(af[mb], bb[nb], acc[mb][nb]);
  }
  if (t < 128) {
    float s = 0.f;
    #pragma unroll
    for (int g = 0; g < 16; ++g) {
      int blk = (g + t) & 15;
      u16x8 v = *(const u16x8*)&ldsA[t * 128 + blk * 8];
      #pragma unroll
      for (int j = 0; j < 8; ++j) s += bf2f(v[j]) * ksl[blk * 8 + j];
    }
    dls[t] = s + 1e-6f;
  }
  __syncthreads();
  const int b = bh >> 4, h = bh & 15;
  u16* oc = ctx + ((size_t)b * 2048 + sl0) * 2048 + h * 128;
  #pragma unroll
  for (int mb = 0; mb < 4; ++mb)
    #pragma unroll
    for (int nb = 0; nb < 4; ++nb)
      #pragma unroll
      for (int j = 0; j < 4; ++j) {
        int srow = wm + mb * 16 + r4 + j;
        int col = wn + nb * 16 + lr;
        oc[(size_t)srow * 2048 + col] = f2bf(acc[mb][nb][j] / dls[srow]);
      }
}

// ---------------- K4: out = ctx @ Wo + bo — 256x256 tile, pipelined ----------
// 8 waves (2M x 4N), BK=32 substeps, 4-slot LDS ring per operand (128 KiB),
// stage 3 substeps ahead, vmcnt(8) once per substep (never drain to 0 in loop),
// T2 XOR swizzle (2-way banks), T5 setprio, T1 XCD swizzle (512 blocks, %8==0).
__global__ __launch_bounds__(512, 2) void mla_out8(
    const u16* __restrict__ ctx, const u16* __restrict__ WoT,
    const float* __restrict__ bo, float* __restrict__ out) {
  __shared__ u16 ldsA[4 * 8192];   // 4 slots x (256 rows x 32 cols) bf16
  __shared__ u16 ldsB[4 * 8192];
  const int t = threadIdx.x;
  const int bid = (int)blockIdx.x;
  const int swz = (bid & 7) * 64 + (bid >> 3);   // bijective, 512 % 8 == 0
  const int mt = swz >> 3, nt = swz & 7;
  const u16* Ag = ctx + (size_t)mt * 256 * 2048;
  const u16* Bg = WoT + (size_t)nt * 256 * 2048;

  // staging: linear LDS dest, pre-swizzled global source column (involution)
  const int o0 = t * 16;                        // byte offset in slot, issue 0
  const int row0 = o0 >> 6;                     // 0..127 (issue 1 adds +128)
  const int c0 = ((((o0 >> 4) & 3) ^ ((row0 >> 1) & 3)) * 8);  // u16 col within substep

  const int w = t >> 6, lane = t & 63;
  const int wrow = (w >> 2) * 128;
  const int wcol = (w & 3) * 64;
  const int lr = lane & 15, hi = lane >> 4, r4 = (lane >> 4) * 4;

  float bocache[4];
  #pragma unroll
  for (int nb = 0; nb < 4; ++nb) bocache[nb] = bo[nt * 256 + wcol + nb * 16 + lr];

  char* lA = (char*)ldsA;
  char* lB = (char*)ldsB;

#define STAGE_A(u) do { const int _sl = ((u) & 3) * 16384; \
    gload16(Ag + (size_t)row0 * 2048 + (u) * 32 + c0, lA + _sl + o0); \
    gload16(Ag + (size_t)(row0 + 128) * 2048 + (u) * 32 + c0, lA + _sl + o0 + 8192); } while (0)
#define STAGE_B(u) do { const int _sl = ((u) & 3) * 16384; \
    gload16(Bg + (size_t)row0 * 2048 + (u) * 32 + c0, lB + _sl + o0); \
    gload16(Bg + (size_t)(row0 + 128) * 2048 + (u) * 32 + c0, lB + _sl + o0 + 8192); } while (0)

  auto rdA = [&](int slotb, int r) -> bf16x8 {
    int p = (r << 6) + (hi << 4);
    p ^= ((r >> 1) & 3) << 4;
    return *(const bf16x8*)(lA + slotb + p);
  };
  auto rdB = [&](int slotb, int r) -> bf16x8 {
    int p = (r << 6) + (hi << 4);
    p ^= ((r >> 1) & 3) << 4;
    return *(const bf16x8*)(lB + slotb + p);
  };

  f32x4 acc0[4][4], acc1[4][4];
  #pragma unroll
  for (int mb = 0; mb < 4; ++mb)
    #pragma unroll
    for (int nb = 0; nb < 4; ++nb) { acc0[mb][nb] = (f32x4)0.f; acc1[mb][nb] = (f32x4)0.f; }

  // prologue: pre-stage substeps 0,1,2 (12 issues); ensure 0 resident
  STAGE_A(0); STAGE_B(0); STAGE_A(1); STAGE_B(1); STAGE_A(2); STAGE_B(2);
  asm volatile("s_waitcnt vmcnt(8)" ::: "memory");
  __builtin_amdgcn_s_barrier();

  bf16x8 af[4], bb[4];

  for (int u = 0; u < 61; ++u) {
    const int sb = (u & 3) * 16384;
    // ---- phase A: m-group 0 ----
    #pragma unroll
    for (int nb = 0; nb < 4; ++nb) bb[nb] = rdB(sb, wcol + nb * 16 + lr);
    #pragma unroll
    for (int mb = 0; mb < 4; ++mb) af[mb] = rdA(sb, wrow + mb * 16 + lr);
    STAGE_A(u + 3);
    __builtin_amdgcn_sched_barrier(0);
    __builtin_amdgcn_s_barrier();
    __builtin_amdgcn_s_setprio(1);
    #pragma unroll
    for (int mb = 0; mb < 4; ++mb)
      #pragma unroll
      for (int nb = 0; nb < 4; ++nb)
        acc0[mb][nb] = mfma16(af[mb], bb[nb], acc0[mb][nb]);
    __builtin_amdgcn_s_setprio(0);
    __builtin_amdgcn_s_barrier();
    // ---- phase B: m-group 1 (reuse bb) ----
    #pragma unroll
    for (int mb = 0; mb < 4; ++mb) af[mb] = rdA(sb, wrow + 64 + mb * 16 + lr);
    STAGE_B(u + 3);
    __builtin_amdgcn_sched_barrier(0);
    __builtin_amdgcn_s_barrier();
    __builtin_amdgcn_s_setprio(1);
    #pragma unroll
    for (int mb = 0; mb < 4; ++mb)
      #pragma unroll
      for (int nb = 0; nb < 4; ++nb)
        acc1[mb][nb] = mfma16(af[mb], bb[nb], acc1[mb][nb]);
    __builtin_amdgcn_s_setprio(0);
    asm volatile("s_waitcnt vmcnt(8)" ::: "memory");  // next substep's A/B resident
    __builtin_amdgcn_s_barrier();
  }

  // tail: substeps 61..63 fully staged; drain once, then pure compute
  asm volatile("s_waitcnt vmcnt(0)" ::: "memory");
  __builtin_amdgcn_s_barrier();
  #pragma unroll
  for (int u = 61; u < 64; ++u) {
    const int sb = (u & 3) * 16384;
    #pragma unroll
    for (int nb = 0; nb < 4; ++nb) bb[nb] = rdB(sb, wcol + nb * 16 + lr);
    #pragma unroll
    for (int mb = 0; mb < 4; ++mb) af[mb] = rdA(sb, wrow + mb * 16 + lr);
    #pragma unroll
    for (int mb = 0; mb < 4; ++mb)
      #pragma unroll
      for (int nb = 0; nb < 4; ++nb)
        acc0[mb][nb] = mfma16(af[mb], bb[nb], acc0[mb][nb]);
    #pragma unroll
    for (int mb = 0; mb < 4; ++mb) af[mb] = rdA(sb, wrow + 64 + mb * 16 + lr);
    #pragma unroll
    for (int mb = 0; mb < 4; ++mb)
      #pragma unroll
      for (int nb = 0; nb < 4; ++nb)
        acc1[mb][nb] = mfma16(af[mb], bb[nb], acc1[mb][nb]);
  }
#undef STAGE_A
#undef STAGE_B

  // epilogue: C += bias, fp32 stores
  const size_t obase = (size_t)(mt * 256 + wrow) * 2048 + nt * 256 + wcol + lr;
  #pragma unroll
  for (int mb = 0; mb < 4; ++mb)
    #pragma unroll
    for (int j = 0; j < 4; ++j) {
      size_t ro = obase + (size_t)(mb * 16 + r4 + j) * 2048;
      #pragma unroll
      for (int nb = 0; nb < 4; ++nb)
        out[ro + nb * 16] = acc0[mb][nb][j] + bocache[nb];
    }
  #pragma unroll
  for (int mb = 0; mb < 4; ++mb)
    #pragma unroll
    for (int j = 0; j < 4; ++j) {
      size_t ro = obase + (size_t)(64 + mb * 16 + r4 + j) * 2048;
      #pragma unroll
      for (int nb = 0; nb < 4; ++nb)
        out[ro + nb * 16] = acc1[mb][nb][j] + bocache[nb];
    }
}

extern "C" void kernel_launch(void* const* d_in, const int* in_sizes, int n_in,
                              void* d_out, int out_size, void* d_ws, size_t ws_size,
                              hipStream_t stream) {
  (void)in_sizes; (void)n_in; (void)out_size;
  const float* X  = (const float*)d_in[0];
  const float* Wq = (const float*)d_in[1];
  const float* Wk = (const float*)d_in[2];
  const float* Wv = (const float*)d_in[3];
  const float* Wo = (const float*)d_in[4];
  const float* bo = (const float*)d_in[5];
  float* out = (float*)d_out;
  char* ws = (char*)d_ws;
  if (ws_size < WS_NEED) return;

  u16*   wqT  = (u16*)(ws + OFF_WQT);
  u16*   wkT  = (u16*)(ws + OFF_WKT);
  u16*   wvT  = (u16*)(ws + OFF_WVT);
  u16*   woT  = (u16*)(ws + OFF_WOT);
  u16*   pq   = (u16*)(ws + OFF_PQ);
  u16*   pkT  = (u16*)(ws + OFF_PKT);
  u16*   vT   = (u16*)(ws + OFF_VT);
  float* kvp  = (float*)(ws + OFF_KVP);
  u16*   kvT  = (u16*)(ws + OFF_KVT);
  float* ksum = (float*)(ws + OFF_KSUM);
  u16*   ctx  = (u16*)(ws + OFF_CTX);

  dim3 tb(32, 8);
  mla_transpose_cvt<<<dim3(4, 4, 16), tb, 0, stream>>>(Wq, wqT, 128);
  mla_transpose_cvt<<<dim3(4, 4, 16), tb, 0, stream>>>(Wk, wkT, 128);
  mla_transpose_cvt<<<dim3(4, 4, 16), tb, 0, stream>>>(Wv, wvT, 128);
  mla_transpose_cvt<<<dim3(64, 64, 1), tb, 0, stream>>>(Wo, woT, 2048);
  mla_qkv<<<dim3(128, 16), 256, 0, stream>>>(X, wqT, wkT, wvT, pq, pkT, vT);
  mla_kv<<<dim3(128, 4), 256, 0, stream>>>(pkT, vT, kvp);
  mla_kvreduce<<<1024, 256, 0, stream>>>(kvp, kvT);
  mla_ksum<<<4096, 256, 0, stream>>>(pkT, ksum);
  mla_ctx<<<dim3(16, 128), 256, 0, stream>>>(pq, kvT, ksum, ctx);
  mla_out8<<<512, 512, 0, stream>>>(ctx, woT, bo, out);
}